// Round 4
// baseline (465.396 us; speedup 1.0000x reference)
//
#include <hip/hip_runtime.h>

typedef unsigned short u16;
typedef unsigned int   u32;
typedef __bf16 bf16x8 __attribute__((ext_vector_type(8)));
typedef float  f32x4  __attribute__((ext_vector_type(4)));

#define N_TOT 2304

__device__ __forceinline__ u16 f32_to_bf16(float f) {
  u32 u = __float_as_uint(f);
  u32 r = (u + 0x7FFFu + ((u >> 16) & 1u)) >> 16;  // RTNE
  return (u16)r;
}
__device__ __forceinline__ float bf16_to_f32(u16 h) {
  return __uint_as_float(((u32)h) << 16);
}

__device__ __forceinline__ void gload_lds16(const void* gsrc, void* lds) {
  __builtin_amdgcn_global_load_lds(
      (const __attribute__((address_space(1))) void*)gsrc,
      (__attribute__((address_space(3))) void*)lds, 16, 0, 0);
}

// ---------- kernel 1: per-task Frobenius sum-of-squares ----------
__global__ void norms_kernel(const float* __restrict__ Aq, const float* __restrict__ Bq,
                             const float* __restrict__ Av, const float* __restrict__ Bv,
                             float* __restrict__ sumsq) {
  int b = blockIdx.x;  // 0..39 : which*10 + t
  int which = b / 10, t = b % 10;
  const float* src =
      (which == 0 ? Aq : which == 1 ? Bq : which == 2 ? Av : Bv) + t * 12288;
  float s = 0.f;
  for (int i = threadIdx.x; i < 12288; i += 256) { float v = src[i]; s += v * v; }
  for (int off = 32; off > 0; off >>= 1) s += __shfl_down(s, off, 64);
  __shared__ float red[4];
  if ((threadIdx.x & 63) == 0) red[threadIdx.x >> 6] = s;
  __syncthreads();
  if (threadIdx.x == 0) sumsq[b] = red[0] + red[1] + red[2] + red[3];
}

// ---------- kernel 2: softmax gate -> folded per-task weights wq/wv ----------
__global__ void weights_kernel(const float* __restrict__ logits, const float* __restrict__ alpha,
                               const float* __restrict__ sumsq,
                               float* __restrict__ wq, float* __restrict__ wv) {
  int t = threadIdx.x;
  if (t >= 10) return;
  float m = -1e30f;
  for (int i = 0; i < 10; ++i) m = fmaxf(m, logits[i]);
  float sum = 0.f;
  for (int i = 0; i < 10; ++i) sum += expf(logits[i] - m);   // TAU = 1.0
  float coef = (expf(logits[t] - m) / sum) * alpha[t];
  wq[t] = coef / (sqrtf(sumsq[t])      * sqrtf(sumsq[10 + t]) + 1e-8f);
  wv[t] = coef / (sqrtf(sumsq[20 + t]) * sqrtf(sumsq[30 + t]) + 1e-8f);
}

// ---------- kernel 3: build W_eff[n][k] = qkv_w + LoRA delta, split bf16 hi/lo ----------
__global__ __launch_bounds__(256) void build_weff(
    const float* __restrict__ qkv_w,
    const float* __restrict__ Aq, const float* __restrict__ Bq,
    const float* __restrict__ Av, const float* __restrict__ Bv,
    const float* __restrict__ wq, const float* __restrict__ wv,
    u16* __restrict__ Whi, u16* __restrict__ Wlo) {
  __shared__ float As[160][64];
  __shared__ float Bs[160][32];
  __shared__ float wsh[16];

  const int k0 = blockIdx.x * 64;
  const int n0 = blockIdx.y * 32;
  const int tid = threadIdx.x;
  const int nl = tid >> 3;
  const int kg = tid & 7;

  float acc[8] = {0, 0, 0, 0, 0, 0, 0, 0};
  const bool is_q = (n0 < 768);
  const bool is_v = (n0 >= 1536);
  if (is_q || is_v) {
    const float* A  = is_q ? Aq : Av;
    const float* Bm = is_q ? Bq : Bv;
    const float* w  = is_q ? wq : wv;
    const int noff = is_q ? n0 : (n0 - 1536);
    for (int i = tid; i < 10240; i += 256)
      As[i >> 6][i & 63] = A[(i >> 6) * 768 + k0 + (i & 63)];
    for (int i = tid; i < 5120; i += 256) {
      int tr = i >> 5, n = i & 31;
      Bs[tr][n] = Bm[(tr >> 4) * 12288 + (noff + n) * 16 + (tr & 15)];
    }
    if (tid < 10) wsh[tid] = w[tid];
    __syncthreads();
    for (int tr = 0; tr < 160; ++tr) {
      float wb = wsh[tr >> 4] * Bs[tr][nl];
#pragma unroll
      for (int j = 0; j < 8; ++j) acc[j] += wb * As[tr][kg * 8 + j];
    }
  }
  const int n = n0 + nl;
  const size_t base = (size_t)n * 768 + k0 + kg * 8;
#pragma unroll
  for (int j = 0; j < 8; ++j) {
    float v = qkv_w[base + j] + acc[j];
    u16 h = f32_to_bf16(v);
    u16 l = f32_to_bf16(v - bf16_to_f32(h));
    Whi[base + j] = h;
    Wlo[base + j] = l;
  }
}

// ---------- kernel 4: split x into bf16 hi/lo ----------
__global__ void split_x(const float* __restrict__ x, u16* __restrict__ Xhi, u16* __restrict__ Xlo) {
  int i4 = blockIdx.x * 256 + threadIdx.x;
  if (i4 >= 3145728) return;
  float4 v = ((const float4*)x)[i4];
  u32 h0 = f32_to_bf16(v.x), h1 = f32_to_bf16(v.y), h2 = f32_to_bf16(v.z), h3 = f32_to_bf16(v.w);
  u32 l0 = f32_to_bf16(v.x - bf16_to_f32((u16)h0));
  u32 l1 = f32_to_bf16(v.y - bf16_to_f32((u16)h1));
  u32 l2 = f32_to_bf16(v.z - bf16_to_f32((u16)h2));
  u32 l3 = f32_to_bf16(v.w - bf16_to_f32((u16)h3));
  ((uint2*)Xhi)[i4] = make_uint2(h0 | (h1 << 16), h2 | (h3 << 16));
  ((uint2*)Xlo)[i4] = make_uint2(l0 | (l1 << 16), l2 | (l3 << 16));
}

// ---------- kernel 5: K-concat split GEMM, fine-phase interleave ----------
// out[16384,2304] = Xcat @ Wcat^T + bias; K-concat regions: xhi*whi | xhi*wlo | xlo*whi.
// BM=BN=256, BK=32, 8 waves(2Mx4N), 4-deep LDS rotation (128KB dyn).
// Per tile, TWO phases (m201 structure: ~16 MFMA + 4-8 ds_reads per phase):
//  E: read a0-3,b0-3 | stage tile t+2 (4 gloads) | bar | lgkm(0) | 16 MFMA | bar
//  O: read a4-7      | vmcnt(4) drains tile t+1  | bar | lgkm(0) | 16 MFMA | bar
// vmcnt never 0 in the loop; tile t+2's 4 loads stay in flight ~3 phases (>HBM lat).
// LDS swizzle: (row R, 16B-slot S) at phys unit P=(R>>1)*8+((S+4*(R&1))^((R>>1)&7));
// staging keeps LDS linear, global source inverse-swizzled (rule 21). Conflict-free
// (R2 measured SQ_LDS_BANK_CONFLICT == 0).
__global__ __launch_bounds__(512, 2) void gemm_kc(
    const u16* __restrict__ Xhi, const u16* __restrict__ Xlo,
    const u16* __restrict__ Whi, const u16* __restrict__ Wlo,
    const float* __restrict__ bias, float* __restrict__ out) {
  extern __shared__ char smem[];  // 131072 bytes

  const int tid  = threadIdx.x;
  const int lane = tid & 63;
  const int wid  = tid >> 6;

  // T1: bijective XCD swizzle (576 % 8 == 0), n-inner for X L2 reuse
  const int bid = blockIdx.x;
  const int swz = (bid & 7) * 72 + (bid >> 3);
  const int m0 = (swz / 9) << 8;
  const int n0 = (swz % 9) << 8;

  const int wm = (wid >> 2) << 7;   // 0 / 128
  const int wn = (wid & 3) << 6;    // 0 / 64 / 128 / 192
  const int fl = lane & 15, fs = lane >> 4;

  // fragment LDS byte offsets (within one 16KB half-tile)
  int aFrag[8], bFrag[4];
#pragma unroll
  for (int i = 0; i < 8; ++i) {
    int R = wm + i * 16 + fl;
    int pr = R >> 1;
    int u = (fs + ((R & 1) << 2)) ^ (pr & 7);
    aFrag[i] = (pr * 8 + u) * 16;
  }
#pragma unroll
  for (int j = 0; j < 4; ++j) {
    int R = wn + j * 16 + fl;
    int pr = R >> 1;
    int u = (fs + ((R & 1) << 2)) ^ (pr & 7);
    bFrag[j] = (pr * 8 + u) * 16;
  }

  // staging precompute (inverse swizzle on the global source)
  int ldsByte[2];
  long aSrcOff[2], bSrcOff[2];
#pragma unroll
  for (int jj = 0; jj < 2; ++jj) {
    int P = jj * 512 + tid;
    int pr = P >> 3, p = P & 7;
    int u = p ^ (pr & 7);
    int r = (pr << 1) | (u >> 2);
    int s = u & 3;
    ldsByte[jj]  = P * 16;
    aSrcOff[jj] = (long)(m0 + r) * 768 + s * 8;
    bSrcOff[jj] = (long)(n0 + r) * 768 + s * 8;
  }

  auto stage = [&](int t2, int bufi) {
    int tc = t2 > 71 ? 71 : t2;
    int reg = tc / 24;
    int ksrc = (tc - reg * 24) << 5;
    const u16* xb = (reg == 2) ? Xlo : Xhi;
    const u16* wb = (reg == 1) ? Wlo : Whi;
    char* base = smem + bufi * 32768;
    gload_lds16(xb + aSrcOff[0] + ksrc, base + ldsByte[0]);
    gload_lds16(xb + aSrcOff[1] + ksrc, base + ldsByte[1]);
    gload_lds16(wb + bSrcOff[0] + ksrc, base + 16384 + ldsByte[0]);
    gload_lds16(wb + bSrcOff[1] + ksrc, base + 16384 + ldsByte[1]);
  };

  f32x4 acc[8][4] = {};

  stage(0, 0);
  stage(1, 1);
  asm volatile("s_waitcnt vmcnt(4)" ::: "memory");   // tile 0 drained; tile 1 in flight
  __builtin_amdgcn_sched_barrier(0);
  __builtin_amdgcn_s_barrier();
  __builtin_amdgcn_sched_barrier(0);

  for (int t = 0; t < 72; ++t) {
    char* bufA = smem + (t & 3) * 32768;
    char* bufB = bufA + 16384;

    // ---- phase E: frags a0-3 + b0-3, stage tile t+2, 16 MFMA ----
    bf16x8 a0 = *(const bf16x8*)(bufA + aFrag[0]);
    bf16x8 a1 = *(const bf16x8*)(bufA + aFrag[1]);
    bf16x8 a2 = *(const bf16x8*)(bufA + aFrag[2]);
    bf16x8 a3 = *(const bf16x8*)(bufA + aFrag[3]);
    bf16x8 b0 = *(const bf16x8*)(bufB + bFrag[0]);
    bf16x8 b1 = *(const bf16x8*)(bufB + bFrag[1]);
    bf16x8 b2 = *(const bf16x8*)(bufB + bFrag[2]);
    bf16x8 b3 = *(const bf16x8*)(bufB + bFrag[3]);
    stage(t + 2, (t + 2) & 3);
    __builtin_amdgcn_sched_barrier(0);
    __builtin_amdgcn_s_barrier();
    asm volatile("s_waitcnt lgkmcnt(0)" ::: "memory");
    __builtin_amdgcn_sched_barrier(0);
    __builtin_amdgcn_s_setprio(1);
    acc[0][0] = __builtin_amdgcn_mfma_f32_16x16x32_bf16(a0, b0, acc[0][0], 0, 0, 0);
    acc[0][1] = __builtin_amdgcn_mfma_f32_16x16x32_bf16(a0, b1, acc[0][1], 0, 0, 0);
    acc[0][2] = __builtin_amdgcn_mfma_f32_16x16x32_bf16(a0, b2, acc[0][2], 0, 0, 0);
    acc[0][3] = __builtin_amdgcn_mfma_f32_16x16x32_bf16(a0, b3, acc[0][3], 0, 0, 0);
    acc[1][0] = __builtin_amdgcn_mfma_f32_16x16x32_bf16(a1, b0, acc[1][0], 0, 0, 0);
    acc[1][1] = __builtin_amdgcn_mfma_f32_16x16x32_bf16(a1, b1, acc[1][1], 0, 0, 0);
    acc[1][2] = __builtin_amdgcn_mfma_f32_16x16x32_bf16(a1, b2, acc[1][2], 0, 0, 0);
    acc[1][3] = __builtin_amdgcn_mfma_f32_16x16x32_bf16(a1, b3, acc[1][3], 0, 0, 0);
    acc[2][0] = __builtin_amdgcn_mfma_f32_16x16x32_bf16(a2, b0, acc[2][0], 0, 0, 0);
    acc[2][1] = __builtin_amdgcn_mfma_f32_16x16x32_bf16(a2, b1, acc[2][1], 0, 0, 0);
    acc[2][2] = __builtin_amdgcn_mfma_f32_16x16x32_bf16(a2, b2, acc[2][2], 0, 0, 0);
    acc[2][3] = __builtin_amdgcn_mfma_f32_16x16x32_bf16(a2, b3, acc[2][3], 0, 0, 0);
    acc[3][0] = __builtin_amdgcn_mfma_f32_16x16x32_bf16(a3, b0, acc[3][0], 0, 0, 0);
    acc[3][1] = __builtin_amdgcn_mfma_f32_16x16x32_bf16(a3, b1, acc[3][1], 0, 0, 0);
    acc[3][2] = __builtin_amdgcn_mfma_f32_16x16x32_bf16(a3, b2, acc[3][2], 0, 0, 0);
    acc[3][3] = __builtin_amdgcn_mfma_f32_16x16x32_bf16(a3, b3, acc[3][3], 0, 0, 0);
    __builtin_amdgcn_s_setprio(0);
    __builtin_amdgcn_sched_barrier(0);
    __builtin_amdgcn_s_barrier();
    __builtin_amdgcn_sched_barrier(0);

    // ---- phase O: frags a4-7, drain tile t+1 (vmcnt 4), 16 MFMA ----
    bf16x8 a4 = *(const bf16x8*)(bufA + aFrag[4]);
    bf16x8 a5 = *(const bf16x8*)(bufA + aFrag[5]);
    bf16x8 a6 = *(const bf16x8*)(bufA + aFrag[6]);
    bf16x8 a7 = *(const bf16x8*)(bufA + aFrag[7]);
    asm volatile("s_waitcnt vmcnt(4)" ::: "memory");
    __builtin_amdgcn_sched_barrier(0);
    __builtin_amdgcn_s_barrier();
    asm volatile("s_waitcnt lgkmcnt(0)" ::: "memory");
    __builtin_amdgcn_sched_barrier(0);
    __builtin_amdgcn_s_setprio(1);
    acc[4][0] = __builtin_amdgcn_mfma_f32_16x16x32_bf16(a4, b0, acc[4][0], 0, 0, 0);
    acc[4][1] = __builtin_amdgcn_mfma_f32_16x16x32_bf16(a4, b1, acc[4][1], 0, 0, 0);
    acc[4][2] = __builtin_amdgcn_mfma_f32_16x16x32_bf16(a4, b2, acc[4][2], 0, 0, 0);
    acc[4][3] = __builtin_amdgcn_mfma_f32_16x16x32_bf16(a4, b3, acc[4][3], 0, 0, 0);
    acc[5][0] = __builtin_amdgcn_mfma_f32_16x16x32_bf16(a5, b0, acc[5][0], 0, 0, 0);
    acc[5][1] = __builtin_amdgcn_mfma_f32_16x16x32_bf16(a5, b1, acc[5][1], 0, 0, 0);
    acc[5][2] = __builtin_amdgcn_mfma_f32_16x16x32_bf16(a5, b2, acc[5][2], 0, 0, 0);
    acc[5][3] = __builtin_amdgcn_mfma_f32_16x16x32_bf16(a5, b3, acc[5][3], 0, 0, 0);
    acc[6][0] = __builtin_amdgcn_mfma_f32_16x16x32_bf16(a6, b0, acc[6][0], 0, 0, 0);
    acc[6][1] = __builtin_amdgcn_mfma_f32_16x16x32_bf16(a6, b1, acc[6][1], 0, 0, 0);
    acc[6][2] = __builtin_amdgcn_mfma_f32_16x16x32_bf16(a6, b2, acc[6][2], 0, 0, 0);
    acc[6][3] = __builtin_amdgcn_mfma_f32_16x16x32_bf16(a6, b3, acc[6][3], 0, 0, 0);
    acc[7][0] = __builtin_amdgcn_mfma_f32_16x16x32_bf16(a7, b0, acc[7][0], 0, 0, 0);
    acc[7][1] = __builtin_amdgcn_mfma_f32_16x16x32_bf16(a7, b1, acc[7][1], 0, 0, 0);
    acc[7][2] = __builtin_amdgcn_mfma_f32_16x16x32_bf16(a7, b2, acc[7][2], 0, 0, 0);
    acc[7][3] = __builtin_amdgcn_mfma_f32_16x16x32_bf16(a7, b3, acc[7][3], 0, 0, 0);
    __builtin_amdgcn_s_setprio(0);
    __builtin_amdgcn_sched_barrier(0);
    __builtin_amdgcn_s_barrier();
    __builtin_amdgcn_sched_barrier(0);
  }

  // epilogue: C/D layout col=lane&15, row=(lane>>4)*4+reg [HW-verified]
#pragma unroll
  for (int j = 0; j < 4; ++j) {
    const int n = n0 + wn + j * 16 + fl;
    const float bj = bias[n];
#pragma unroll
    for (int i = 0; i < 8; ++i) {
      const int mbase = m0 + wm + i * 16 + (fs << 2);
#pragma unroll
      for (int r = 0; r < 4; ++r)
        out[(size_t)(mbase + r) * N_TOT + n] = acc[i][j][r] + bj;
    }
  }
}

extern "C" void kernel_launch(void* const* d_in, const int* in_sizes, int n_in,
                              void* d_out, int out_size, void* d_ws, size_t ws_size,
                              hipStream_t stream) {
  const float* x     = (const float*)d_in[0];
  const float* Aq    = (const float*)d_in[1];
  const float* Bq    = (const float*)d_in[2];
  const float* Av    = (const float*)d_in[3];
  const float* Bv    = (const float*)d_in[4];
  const float* qkvw  = (const float*)d_in[5];
  const float* qkvb  = (const float*)d_in[6];
  const float* gate  = (const float*)d_in[7];
  const float* alpha = (const float*)d_in[8];
  float* out = (float*)d_out;

  char* ws = (char*)d_ws;
  float* sumsq = (float*)ws;
  float* wq    = (float*)(ws + 256);
  float* wv    = (float*)(ws + 512);
  u16* Whi = (u16*)(ws + 1024);
  u16* Wlo = Whi + 1769472;
  u16* Xhi = Wlo + 1769472;
  u16* Xlo = Xhi + 12582912;

  // unconditional (no call-count-dependent behavior); host-side, graph-safe
  hipFuncSetAttribute((const void*)gemm_kc,
                      hipFuncAttributeMaxDynamicSharedMemorySize, 131072);

  hipLaunchKernelGGL(norms_kernel,   dim3(40),     dim3(256), 0, stream, Aq, Bq, Av, Bv, sumsq);
  hipLaunchKernelGGL(weights_kernel, dim3(1),      dim3(64),  0, stream, gate, alpha, sumsq, wq, wv);
  hipLaunchKernelGGL(build_weff,     dim3(12, 72), dim3(256), 0, stream, qkvw, Aq, Bq, Av, Bv, wq, wv, Whi, Wlo);
  hipLaunchKernelGGL(split_x,        dim3(12288),  dim3(256), 0, stream, x, Xhi, Xlo);
  hipLaunchKernelGGL(gemm_kc,        dim3(576),    dim3(512), 131072, stream,
                     Xhi, Xlo, Whi, Wlo, qkvb, out);
}

// Round 5
// 380.931 us; speedup vs baseline: 1.2217x; 1.2217x over previous
//
#include <hip/hip_runtime.h>

typedef unsigned short u16;
typedef unsigned int   u32;
typedef __bf16 bf16x8 __attribute__((ext_vector_type(8)));
typedef float  f32x4  __attribute__((ext_vector_type(4)));

#define N_TOT 2304

__device__ __forceinline__ u16 f32_to_bf16(float f) {
  u32 u = __float_as_uint(f);
  u32 r = (u + 0x7FFFu + ((u >> 16) & 1u)) >> 16;  // RTNE
  return (u16)r;
}
__device__ __forceinline__ float bf16_to_f32(u16 h) {
  return __uint_as_float(((u32)h) << 16);
}

__device__ __forceinline__ void gload_lds16(const void* gsrc, void* lds) {
  __builtin_amdgcn_global_load_lds(
      (const __attribute__((address_space(1))) void*)gsrc,
      (__attribute__((address_space(3))) void*)lds, 16, 0, 0);
}

// ---------- kernel 1: per-task Frobenius sum-of-squares ----------
__global__ void norms_kernel(const float* __restrict__ Aq, const float* __restrict__ Bq,
                             const float* __restrict__ Av, const float* __restrict__ Bv,
                             float* __restrict__ sumsq) {
  int b = blockIdx.x;  // 0..39 : which*10 + t
  int which = b / 10, t = b % 10;
  const float* src =
      (which == 0 ? Aq : which == 1 ? Bq : which == 2 ? Av : Bv) + t * 12288;
  float s = 0.f;
  for (int i = threadIdx.x; i < 12288; i += 256) { float v = src[i]; s += v * v; }
  for (int off = 32; off > 0; off >>= 1) s += __shfl_down(s, off, 64);
  __shared__ float red[4];
  if ((threadIdx.x & 63) == 0) red[threadIdx.x >> 6] = s;
  __syncthreads();
  if (threadIdx.x == 0) sumsq[b] = red[0] + red[1] + red[2] + red[3];
}

// ---------- kernel 2: softmax gate -> folded per-task weights wq/wv ----------
__global__ void weights_kernel(const float* __restrict__ logits, const float* __restrict__ alpha,
                               const float* __restrict__ sumsq,
                               float* __restrict__ wq, float* __restrict__ wv) {
  int t = threadIdx.x;
  if (t >= 10) return;
  float m = -1e30f;
  for (int i = 0; i < 10; ++i) m = fmaxf(m, logits[i]);
  float sum = 0.f;
  for (int i = 0; i < 10; ++i) sum += expf(logits[i] - m);   // TAU = 1.0
  float coef = (expf(logits[t] - m) / sum) * alpha[t];
  wq[t] = coef / (sqrtf(sumsq[t])      * sqrtf(sumsq[10 + t]) + 1e-8f);
  wv[t] = coef / (sqrtf(sumsq[20 + t]) * sqrtf(sumsq[30 + t]) + 1e-8f);
}

// ---------- kernel 3: build W_eff[n][k] = qkv_w + LoRA delta, split bf16 hi/lo ----------
__global__ __launch_bounds__(256) void build_weff(
    const float* __restrict__ qkv_w,
    const float* __restrict__ Aq, const float* __restrict__ Bq,
    const float* __restrict__ Av, const float* __restrict__ Bv,
    const float* __restrict__ wq, const float* __restrict__ wv,
    u16* __restrict__ Whi, u16* __restrict__ Wlo) {
  __shared__ float As[160][64];
  __shared__ float Bs[160][32];
  __shared__ float wsh[16];

  const int k0 = blockIdx.x * 64;
  const int n0 = blockIdx.y * 32;
  const int tid = threadIdx.x;
  const int nl = tid >> 3;
  const int kg = tid & 7;

  float acc[8] = {0, 0, 0, 0, 0, 0, 0, 0};
  const bool is_q = (n0 < 768);
  const bool is_v = (n0 >= 1536);
  if (is_q || is_v) {
    const float* A  = is_q ? Aq : Av;
    const float* Bm = is_q ? Bq : Bv;
    const float* w  = is_q ? wq : wv;
    const int noff = is_q ? n0 : (n0 - 1536);
    for (int i = tid; i < 10240; i += 256)
      As[i >> 6][i & 63] = A[(i >> 6) * 768 + k0 + (i & 63)];
    for (int i = tid; i < 5120; i += 256) {
      int tr = i >> 5, n = i & 31;
      Bs[tr][n] = Bm[(tr >> 4) * 12288 + (noff + n) * 16 + (tr & 15)];
    }
    if (tid < 10) wsh[tid] = w[tid];
    __syncthreads();
    for (int tr = 0; tr < 160; ++tr) {
      float wb = wsh[tr >> 4] * Bs[tr][nl];
#pragma unroll
      for (int j = 0; j < 8; ++j) acc[j] += wb * As[tr][kg * 8 + j];
    }
  }
  const int n = n0 + nl;
  const size_t base = (size_t)n * 768 + k0 + kg * 8;
#pragma unroll
  for (int j = 0; j < 8; ++j) {
    float v = qkv_w[base + j] + acc[j];
    u16 h = f32_to_bf16(v);
    u16 l = f32_to_bf16(v - bf16_to_f32(h));
    Whi[base + j] = h;
    Wlo[base + j] = l;
  }
}

// ---------- kernel 4: x -> bf16 (hi only; 2-term split drops xlo) ----------
__global__ void split_x(const float* __restrict__ x, u16* __restrict__ Xhi) {
  int i4 = blockIdx.x * 256 + threadIdx.x;
  if (i4 >= 3145728) return;
  float4 v = ((const float4*)x)[i4];
  u32 h0 = f32_to_bf16(v.x), h1 = f32_to_bf16(v.y), h2 = f32_to_bf16(v.z), h3 = f32_to_bf16(v.w);
  ((uint2*)Xhi)[i4] = make_uint2(h0 | (h1 << 16), h2 | (h3 << 16));
}

// ---------- kernel 5: K-concat GEMM with register-level fragment pipeline ----------
// out = bf16(x) @ (Whi + Wlo)^T + bias  as K-concat: region0 Xhi*Whi, region1 Xhi*Wlo.
// 48 K-tiles of BK=32 (K_eff=1536). BM=BN=256, 8 waves(2Mx4N), 4-deep LDS rotation.
// Per tile t (ONE barrier):
//   read a4-7(t)          [4 ds]   | stage(t+2) [4 gloads]
//   cluster1: 16 MFMA a0-3(t)xb(t) -- a4-7 drain overlaps (compiler lgkmcnt(4))
//   vmcnt(4) (t+1 drained; t+2 in flight) ; s_barrier (publish t+1)
//   read b0-3,a0-3(t+1) into OTHER reg set   [8 ds]
//   cluster2: 16 MFMA a4-7(t)xb(t) -- next-tile G1 drain overlaps (lgkmcnt(8))
// G1 set (a0-3,b0-3) double-buffered via unroll-2 static names (rule #20);
// a4-7 single set. LDS swizzle as R2 (verified conflict-free: SQ_LDS_BANK_CONFLICT=0).
__global__ __launch_bounds__(512, 2) void gemm_kc(
    const u16* __restrict__ Xhi,
    const u16* __restrict__ Whi, const u16* __restrict__ Wlo,
    const float* __restrict__ bias, float* __restrict__ out) {
  extern __shared__ char smem[];  // 131072 bytes

  const int tid  = threadIdx.x;
  const int lane = tid & 63;
  const int wid  = tid >> 6;

  // T1: bijective XCD swizzle (576 % 8 == 0), n-inner for X L2 reuse
  const int bid = blockIdx.x;
  const int swz = (bid & 7) * 72 + (bid >> 3);
  const int m0 = (swz / 9) << 8;
  const int n0 = (swz % 9) << 8;

  const int wm = (wid >> 2) << 7;   // 0 / 128
  const int wn = (wid & 3) << 6;    // 0 / 64 / 128 / 192
  const int fl = lane & 15, fs = lane >> 4;

  // fragment LDS byte offsets (within one 16KB half-tile), swizzled
  int aFrag[8], bFrag[4];
#pragma unroll
  for (int i = 0; i < 8; ++i) {
    int R = wm + i * 16 + fl;
    int pr = R >> 1;
    int u = (fs + ((R & 1) << 2)) ^ (pr & 7);
    aFrag[i] = (pr * 8 + u) * 16;
  }
#pragma unroll
  for (int j = 0; j < 4; ++j) {
    int R = wn + j * 16 + fl;
    int pr = R >> 1;
    int u = (fs + ((R & 1) << 2)) ^ (pr & 7);
    bFrag[j] = (pr * 8 + u) * 16;
  }

  // staging precompute (inverse swizzle on the global source); 32-bit offsets
  int ldsByte[2];
  int aSrcOff[2], bSrcOff[2];
#pragma unroll
  for (int jj = 0; jj < 2; ++jj) {
    int P = jj * 512 + tid;
    int pr = P >> 3, p = P & 7;
    int u = p ^ (pr & 7);
    int r = (pr << 1) | (u >> 2);
    int s = u & 3;
    ldsByte[jj] = P * 16;
    aSrcOff[jj] = (m0 + r) * 768 + s * 8;
    bSrcOff[jj] = (n0 + r) * 768 + s * 8;
  }

  auto stage = [&](int t2, int bufi) {
    int tc = t2 > 47 ? 47 : t2;
    int kk = tc >= 24 ? tc - 24 : tc;
    const u16* wb = tc >= 24 ? Wlo : Whi;
    int ksrc = kk << 5;
    char* base = smem + bufi * 32768;
    gload_lds16(Xhi + aSrcOff[0] + ksrc, base + ldsByte[0]);
    gload_lds16(Xhi + aSrcOff[1] + ksrc, base + ldsByte[1]);
    gload_lds16(wb + bSrcOff[0] + ksrc, base + 16384 + ldsByte[0]);
    gload_lds16(wb + bSrcOff[1] + ksrc, base + 16384 + ldsByte[1]);
  };

  f32x4 acc[8][4] = {};
  bf16x8 aX[4], bX[4], aY[4], bY[4], g2[4];

#define CLUSTER1(CA, CB)                                                              \
  __builtin_amdgcn_s_setprio(1);                                                      \
  acc[0][0] = __builtin_amdgcn_mfma_f32_16x16x32_bf16(CA[0], CB[0], acc[0][0], 0, 0, 0); \
  acc[0][1] = __builtin_amdgcn_mfma_f32_16x16x32_bf16(CA[0], CB[1], acc[0][1], 0, 0, 0); \
  acc[0][2] = __builtin_amdgcn_mfma_f32_16x16x32_bf16(CA[0], CB[2], acc[0][2], 0, 0, 0); \
  acc[0][3] = __builtin_amdgcn_mfma_f32_16x16x32_bf16(CA[0], CB[3], acc[0][3], 0, 0, 0); \
  acc[1][0] = __builtin_amdgcn_mfma_f32_16x16x32_bf16(CA[1], CB[0], acc[1][0], 0, 0, 0); \
  acc[1][1] = __builtin_amdgcn_mfma_f32_16x16x32_bf16(CA[1], CB[1], acc[1][1], 0, 0, 0); \
  acc[1][2] = __builtin_amdgcn_mfma_f32_16x16x32_bf16(CA[1], CB[2], acc[1][2], 0, 0, 0); \
  acc[1][3] = __builtin_amdgcn_mfma_f32_16x16x32_bf16(CA[1], CB[3], acc[1][3], 0, 0, 0); \
  acc[2][0] = __builtin_amdgcn_mfma_f32_16x16x32_bf16(CA[2], CB[0], acc[2][0], 0, 0, 0); \
  acc[2][1] = __builtin_amdgcn_mfma_f32_16x16x32_bf16(CA[2], CB[1], acc[2][1], 0, 0, 0); \
  acc[2][2] = __builtin_amdgcn_mfma_f32_16x16x32_bf16(CA[2], CB[2], acc[2][2], 0, 0, 0); \
  acc[2][3] = __builtin_amdgcn_mfma_f32_16x16x32_bf16(CA[2], CB[3], acc[2][3], 0, 0, 0); \
  acc[3][0] = __builtin_amdgcn_mfma_f32_16x16x32_bf16(CA[3], CB[0], acc[3][0], 0, 0, 0); \
  acc[3][1] = __builtin_amdgcn_mfma_f32_16x16x32_bf16(CA[3], CB[1], acc[3][1], 0, 0, 0); \
  acc[3][2] = __builtin_amdgcn_mfma_f32_16x16x32_bf16(CA[3], CB[2], acc[3][2], 0, 0, 0); \
  acc[3][3] = __builtin_amdgcn_mfma_f32_16x16x32_bf16(CA[3], CB[3], acc[3][3], 0, 0, 0); \
  __builtin_amdgcn_s_setprio(0);

#define CLUSTER2(CB)                                                                  \
  __builtin_amdgcn_s_setprio(1);                                                      \
  acc[4][0] = __builtin_amdgcn_mfma_f32_16x16x32_bf16(g2[0], CB[0], acc[4][0], 0, 0, 0); \
  acc[4][1] = __builtin_amdgcn_mfma_f32_16x16x32_bf16(g2[0], CB[1], acc[4][1], 0, 0, 0); \
  acc[4][2] = __builtin_amdgcn_mfma_f32_16x16x32_bf16(g2[0], CB[2], acc[4][2], 0, 0, 0); \
  acc[4][3] = __builtin_amdgcn_mfma_f32_16x16x32_bf16(g2[0], CB[3], acc[4][3], 0, 0, 0); \
  acc[5][0] = __builtin_amdgcn_mfma_f32_16x16x32_bf16(g2[1], CB[0], acc[5][0], 0, 0, 0); \
  acc[5][1] = __builtin_amdgcn_mfma_f32_16x16x32_bf16(g2[1], CB[1], acc[5][1], 0, 0, 0); \
  acc[5][2] = __builtin_amdgcn_mfma_f32_16x16x32_bf16(g2[1], CB[2], acc[5][2], 0, 0, 0); \
  acc[5][3] = __builtin_amdgcn_mfma_f32_16x16x32_bf16(g2[1], CB[3], acc[5][3], 0, 0, 0); \
  acc[6][0] = __builtin_amdgcn_mfma_f32_16x16x32_bf16(g2[2], CB[0], acc[6][0], 0, 0, 0); \
  acc[6][1] = __builtin_amdgcn_mfma_f32_16x16x32_bf16(g2[2], CB[1], acc[6][1], 0, 0, 0); \
  acc[6][2] = __builtin_amdgcn_mfma_f32_16x16x32_bf16(g2[2], CB[2], acc[6][2], 0, 0, 0); \
  acc[6][3] = __builtin_amdgcn_mfma_f32_16x16x32_bf16(g2[2], CB[3], acc[6][3], 0, 0, 0); \
  acc[7][0] = __builtin_amdgcn_mfma_f32_16x16x32_bf16(g2[3], CB[0], acc[7][0], 0, 0, 0); \
  acc[7][1] = __builtin_amdgcn_mfma_f32_16x16x32_bf16(g2[3], CB[1], acc[7][1], 0, 0, 0); \
  acc[7][2] = __builtin_amdgcn_mfma_f32_16x16x32_bf16(g2[3], CB[2], acc[7][2], 0, 0, 0); \
  acc[7][3] = __builtin_amdgcn_mfma_f32_16x16x32_bf16(g2[3], CB[3], acc[7][3], 0, 0, 0); \
  __builtin_amdgcn_s_setprio(0);

#define TILE_BODY(T, CA, CB, NA, NB)                                           \
  {                                                                            \
    const int tcur = (T);                                                      \
    char* bufA = smem + (tcur & 3) * 32768;                                    \
    g2[0] = *(const bf16x8*)(bufA + aFrag[4]);                                 \
    g2[1] = *(const bf16x8*)(bufA + aFrag[5]);                                 \
    g2[2] = *(const bf16x8*)(bufA + aFrag[6]);                                 \
    g2[3] = *(const bf16x8*)(bufA + aFrag[7]);                                 \
    stage(tcur + 2, (tcur + 2) & 3);                                           \
    __builtin_amdgcn_sched_barrier(0);                                         \
    CLUSTER1(CA, CB)                                                           \
    __builtin_amdgcn_sched_barrier(0);                                         \
    asm volatile("s_waitcnt vmcnt(4)" ::: "memory");                           \
    __builtin_amdgcn_sched_barrier(0);                                         \
    __builtin_amdgcn_s_barrier();                                              \
    __builtin_amdgcn_sched_barrier(0);                                         \
    char* nA = smem + ((tcur + 1) & 3) * 32768;                                \
    char* nB = nA + 16384;                                                     \
    NB[0] = *(const bf16x8*)(nB + bFrag[0]);                                   \
    NB[1] = *(const bf16x8*)(nB + bFrag[1]);                                   \
    NB[2] = *(const bf16x8*)(nB + bFrag[2]);                                   \
    NB[3] = *(const bf16x8*)(nB + bFrag[3]);                                   \
    NA[0] = *(const bf16x8*)(nA + aFrag[0]);                                   \
    NA[1] = *(const bf16x8*)(nA + aFrag[1]);                                   \
    NA[2] = *(const bf16x8*)(nA + aFrag[2]);                                   \
    NA[3] = *(const bf16x8*)(nA + aFrag[3]);                                   \
    __builtin_amdgcn_sched_barrier(0);                                         \
    CLUSTER2(CB)                                                               \
    __builtin_amdgcn_sched_barrier(0);                                         \
  }

  // prologue: stage tiles 0,1; publish 0; preload G1(0) into set X
  stage(0, 0);
  stage(1, 1);
  asm volatile("s_waitcnt vmcnt(4)" ::: "memory");
  __builtin_amdgcn_sched_barrier(0);
  __builtin_amdgcn_s_barrier();
  __builtin_amdgcn_sched_barrier(0);
  {
    char* bA = smem;
    char* bB = smem + 16384;
    bX[0] = *(const bf16x8*)(bB + bFrag[0]);
    bX[1] = *(const bf16x8*)(bB + bFrag[1]);
    bX[2] = *(const bf16x8*)(bB + bFrag[2]);
    bX[3] = *(const bf16x8*)(bB + bFrag[3]);
    aX[0] = *(const bf16x8*)(bA + aFrag[0]);
    aX[1] = *(const bf16x8*)(bA + aFrag[1]);
    aX[2] = *(const bf16x8*)(bA + aFrag[2]);
    aX[3] = *(const bf16x8*)(bA + aFrag[3]);
  }

  for (int tt = 0; tt < 48; tt += 2) {
    TILE_BODY(tt,     aX, bX, aY, bY)
    TILE_BODY(tt + 1, aY, bY, aX, bX)
  }

  // epilogue: C/D layout col=lane&15, row=(lane>>4)*4+reg [HW-verified]
#pragma unroll
  for (int j = 0; j < 4; ++j) {
    const int n = n0 + wn + j * 16 + fl;
    const float bj = bias[n];
#pragma unroll
    for (int i = 0; i < 8; ++i) {
      const int mbase = m0 + wm + i * 16 + (fs << 2);
#pragma unroll
      for (int r = 0; r < 4; ++r)
        out[(size_t)(mbase + r) * N_TOT + n] = acc[i][j][r] + bj;
    }
  }
#undef TILE_BODY
#undef CLUSTER1
#undef CLUSTER2
}

extern "C" void kernel_launch(void* const* d_in, const int* in_sizes, int n_in,
                              void* d_out, int out_size, void* d_ws, size_t ws_size,
                              hipStream_t stream) {
  const float* x     = (const float*)d_in[0];
  const float* Aq    = (const float*)d_in[1];
  const float* Bq    = (const float*)d_in[2];
  const float* Av    = (const float*)d_in[3];
  const float* Bv    = (const float*)d_in[4];
  const float* qkvw  = (const float*)d_in[5];
  const float* qkvb  = (const float*)d_in[6];
  const float* gate  = (const float*)d_in[7];
  const float* alpha = (const float*)d_in[8];
  float* out = (float*)d_out;

  char* ws = (char*)d_ws;
  float* sumsq = (float*)ws;
  float* wq    = (float*)(ws + 256);
  float* wv    = (float*)(ws + 512);
  u16* Whi = (u16*)(ws + 1024);
  u16* Wlo = Whi + 1769472;
  u16* Xhi = Wlo + 1769472;   // 16384*768 bf16; Xlo no longer used

  hipFuncSetAttribute((const void*)gemm_kc,
                      hipFuncAttributeMaxDynamicSharedMemorySize, 131072);

  hipLaunchKernelGGL(norms_kernel,   dim3(40),     dim3(256), 0, stream, Aq, Bq, Av, Bv, sumsq);
  hipLaunchKernelGGL(weights_kernel, dim3(1),      dim3(64),  0, stream, gate, alpha, sumsq, wq, wv);
  hipLaunchKernelGGL(build_weff,     dim3(12, 72), dim3(256), 0, stream, qkvw, Aq, Bq, Av, Bv, wq, wv, Whi, Wlo);
  hipLaunchKernelGGL(split_x,        dim3(12288),  dim3(256), 0, stream, x, Xhi);
  hipLaunchKernelGGL(gemm_kc,        dim3(576),    dim3(512), 131072, stream,
                     Xhi, Whi, Wlo, qkvb, out);
}